// Round 1
// baseline (266.363 us; speedup 1.0000x reference)
//
#include <hip/hip_runtime.h>

// Problem constants: z0 (2,512,128), z1 (2,512,128), W (64,256), out (2,64,512,512)
#define NBATCH 2
#define LL 512
#define DDIM 128
#define HCH 64
#define NBLOCKS 2048  // 2 * 32 * 32

typedef float f32x4 __attribute__((ext_vector_type(4)));
typedef __bf16 bf16x8 __attribute__((ext_vector_type(8)));

__device__ __forceinline__ float elu_f(float v) {
  return v > 0.0f ? v : (__expf(v) - 1.0f);
}

// Pre-convert W (64x256 f32) into MFMA A-fragment order, bf16.
// Slot s = (chunk ck 0..7, htile 0..3, lane 0..63): holds W[ht*16+(l&15)][ck*32+8*(l>>4) + j], j=0..7
__global__ void wprep_kernel(const float* __restrict__ w, bf16x8* __restrict__ wf) {
  int s = blockIdx.x * 256 + threadIdx.x;  // 0..2047
  int ck = s >> 8;
  int rem = s & 255;
  int ht = rem >> 6;
  int l = rem & 63;
  int h = ht * 16 + (l & 15);
  int c = ck * 32 + ((l >> 4) << 3);
  const float* src = w + h * 256 + c;
  bf16x8 v;
#pragma unroll
  for (int j = 0; j < 8; ++j) v[j] = (__bf16)src[j];
  wf[s] = v;
}

// PASS 0: compute ELU(conv(features)) and per-block per-channel sum/sumsq partials.
// PASS 1: recompute, apply BN scale/shift, write output.
template <int PASS>
__global__ __launch_bounds__(256, 2) void fused_kernel(
    const float* __restrict__ z0g, const float* __restrict__ z1g,
    const bf16x8* __restrict__ wf, const float* __restrict__ cb,
    const float* __restrict__ sstab, float* __restrict__ partials,
    float* __restrict__ out) {
  __shared__ float z0_lds[16 * 128];     // 8 KB, row-major [x_local][c]
  __shared__ f32x4 z1f[2][4 * 64];       // 8 KB, B-frag order: [plane][ck*64+lane]
  __shared__ float sred[128];            // per-channel sum / sumsq (PASS0)
  __shared__ float cb_lds[64];
  __shared__ float sc_lds[128];          // scale[64], shift[64] (PASS1)

  const int t = threadIdx.x;
  const int lane = t & 63;
  const int wv = t >> 6;
  const int bid = blockIdx.x;
  const int by = bid & 31, bx = (bid >> 5) & 31, n = bid >> 10;
  const int x0 = bx * 16, y0 = by * 16;

  // ---- staging: z0 tile linear, z1 tile swizzled to fragment order ----
  {
    int r = t >> 4, cs = t & 15;  // row 0..15, 8-float column segment 0..15
    const f32x4* g0 = (const f32x4*)(z0g + (size_t)(n * LL + x0 + r) * DDIM + cs * 8);
    const f32x4* g1 = (const f32x4*)(z1g + (size_t)(n * LL + y0 + r) * DDIM + cs * 8);
    f32x4 a0 = g0[0], a1 = g0[1];
    f32x4 b0 = g1[0], b1 = g1[1];
    ((f32x4*)z0_lds)[r * 32 + cs * 2 + 0] = a0;
    ((f32x4*)z0_lds)[r * 32 + cs * 2 + 1] = a1;
    // c = cs*8 .. cs*8+7  ->  chunk ck = cs>>2, lane group g = cs&3, frag lane = g*16 + r
    int ck = cs >> 2, gg = cs & 3, fl = gg * 16 + r;
    z1f[0][ck * 64 + fl] = b0;
    z1f[1][ck * 64 + fl] = b1;
    if (t < 128) sred[t] = 0.0f;
    if (t < 64) cb_lds[t] = cb[t];
    if (PASS == 1 && t < 128) sc_lds[t] = sstab[t];
  }
  __syncthreads();

  f32x4 acc[4][4];  // [xi][htile]
  const f32x4 zero4 = {0.f, 0.f, 0.f, 0.f};
#pragma unroll
  for (int xi = 0; xi < 4; ++xi)
#pragma unroll
    for (int ht = 0; ht < 4; ++ht) acc[xi][ht] = zero4;

#pragma unroll
  for (int ck = 0; ck < 8; ++ck) {
    const int ckz = ck & 3;  // z-data chunk (dif chunks 0..3 reuse same z as mul chunks 4..7)
    bf16x8 af[4];
#pragma unroll
    for (int ht = 0; ht < 4; ++ht) af[ht] = wf[(ck * 4 + ht) * 64 + lane];
    f32x4 b0 = z1f[0][ckz * 64 + lane];
    f32x4 b1 = z1f[1][ckz * 64 + lane];
#pragma unroll
    for (int xi = 0; xi < 4; ++xi) {
      const int xl = wv * 4 + xi;
      const f32x4* z0p = (const f32x4*)&z0_lds[xl * 128 + ckz * 32 + ((lane >> 4) << 3)];
      f32x4 a0 = z0p[0], a1 = z0p[1];
      bf16x8 bfrag;
      if (ck < 4) {
#pragma unroll
        for (int j = 0; j < 4; ++j) {
          bfrag[j] = (__bf16)fabsf(a0[j] - b0[j]);
          bfrag[4 + j] = (__bf16)fabsf(a1[j] - b1[j]);
        }
      } else {
#pragma unroll
        for (int j = 0; j < 4; ++j) {
          bfrag[j] = (__bf16)(a0[j] * b0[j]);
          bfrag[4 + j] = (__bf16)(a1[j] * b1[j]);
        }
      }
#pragma unroll
      for (int ht = 0; ht < 4; ++ht)
        acc[xi][ht] =
            __builtin_amdgcn_mfma_f32_16x16x32_bf16(af[ht], bfrag, acc[xi][ht], 0, 0, 0);
    }
  }

  // ---- epilogue ----
  if (PASS == 0) {
    float s1[4][4], s2[4][4];
#pragma unroll
    for (int ht = 0; ht < 4; ++ht)
#pragma unroll
      for (int i = 0; i < 4; ++i) { s1[ht][i] = 0.f; s2[ht][i] = 0.f; }
#pragma unroll
    for (int xi = 0; xi < 4; ++xi)
#pragma unroll
      for (int ht = 0; ht < 4; ++ht)
#pragma unroll
        for (int i = 0; i < 4; ++i) {
          int h = ht * 16 + ((lane >> 4) << 2) + i;
          float v = elu_f(acc[xi][ht][i] + cb_lds[h]);
          s1[ht][i] += v;
          s2[ht][i] += v * v;
        }
#pragma unroll
    for (int ht = 0; ht < 4; ++ht)
#pragma unroll
      for (int i = 0; i < 4; ++i) {
#pragma unroll
        for (int m = 1; m <= 8; m <<= 1) {
          s1[ht][i] += __shfl_xor(s1[ht][i], m, 64);
          s2[ht][i] += __shfl_xor(s2[ht][i], m, 64);
        }
        if ((lane & 15) == 0) {
          int h = ht * 16 + ((lane >> 4) << 2) + i;
          atomicAdd(&sred[h], s1[ht][i]);
          atomicAdd(&sred[64 + h], s2[ht][i]);
        }
      }
    __syncthreads();
    // partials layout: [channel_slot 0..127][block 0..2047] for coalesced finalize reads
    if (t < 128) partials[(size_t)t * NBLOCKS + bid] = sred[t];
  } else {
#pragma unroll
    for (int xi = 0; xi < 4; ++xi) {
      const int x = x0 + wv * 4 + xi;
#pragma unroll
      for (int ht = 0; ht < 4; ++ht)
#pragma unroll
        for (int i = 0; i < 4; ++i) {
          int h = ht * 16 + ((lane >> 4) << 2) + i;
          float v = elu_f(acc[xi][ht][i] + cb_lds[h]);
          v = v * sc_lds[h] + sc_lds[64 + h];
          out[((size_t)(n * HCH + h) * LL + x) * LL + y0 + (lane & 15)] = v;
        }
    }
  }
}

__global__ void bn_finalize_kernel(const float* __restrict__ partials,
                                   const float* __restrict__ gamma,
                                   const float* __restrict__ beta,
                                   float* __restrict__ sstab) {
  const int h = blockIdx.x, t = threadIdx.x;
  const int lane = t & 63, wv = t >> 6;
  float s1 = 0.f, s2 = 0.f;
  for (int b = t; b < NBLOCKS; b += 256) {
    s1 += partials[(size_t)h * NBLOCKS + b];
    s2 += partials[(size_t)(64 + h) * NBLOCKS + b];
  }
#pragma unroll
  for (int m = 1; m <= 32; m <<= 1) {
    s1 += __shfl_xor(s1, m, 64);
    s2 += __shfl_xor(s2, m, 64);
  }
  __shared__ float r1[4], r2[4];
  if (lane == 0) { r1[wv] = s1; r2[wv] = s2; }
  __syncthreads();
  if (t == 0) {
    float S1 = r1[0] + r1[1] + r1[2] + r1[3];
    float S2 = r2[0] + r2[1] + r2[2] + r2[3];
    const float M = 524288.0f;  // 2 * 512 * 512
    float mean = S1 / M;
    float var = S2 / M - mean * mean;
    var = var < 0.f ? 0.f : var;
    float sc = gamma[h] * rsqrtf(var + 1e-5f);
    sstab[h] = sc;
    sstab[64 + h] = beta[h] - mean * sc;
  }
}

extern "C" void kernel_launch(void* const* d_in, const int* in_sizes, int n_in,
                              void* d_out, int out_size, void* d_ws, size_t ws_size,
                              hipStream_t stream) {
  (void)in_sizes; (void)n_in; (void)out_size; (void)ws_size;
  const float* z0 = (const float*)d_in[0];
  const float* z1 = (const float*)d_in[1];
  const float* w = (const float*)d_in[2];
  const float* cb = (const float*)d_in[3];
  const float* gamma = (const float*)d_in[4];
  const float* beta = (const float*)d_in[5];
  float* out = (float*)d_out;

  char* ws = (char*)d_ws;
  bf16x8* wf = (bf16x8*)ws;                                   // 32 KB
  float* partials = (float*)(ws + 32768);                     // 128 * 2048 * 4 = 1 MB
  float* sstab = (float*)(ws + 32768 + 128 * NBLOCKS * 4);    // 128 floats

  wprep_kernel<<<8, 256, 0, stream>>>(w, wf);
  fused_kernel<0><<<NBLOCKS, 256, 0, stream>>>(z0, z1, wf, cb, nullptr, partials, nullptr);
  bn_finalize_kernel<<<64, 256, 0, stream>>>(partials, gamma, beta, sstab);
  fused_kernel<1><<<NBLOCKS, 256, 0, stream>>>(z0, z1, wf, cb, sstab, partials, out);
}

// Round 2
// 204.059 us; speedup vs baseline: 1.3053x; 1.3053x over previous
//
#include <hip/hip_runtime.h>

// Problem constants: z0 (2,512,128), z1 (2,512,128), W (64,256), out (2,64,512,512)
#define NBATCH 2
#define LL 512
#define DDIM 128
#define HCH 64
#define NBLOCKS 1024  // 2 * 32 * 16   (n, bx, by) ; tile = 16x * 32y * 64h

typedef float f32x4 __attribute__((ext_vector_type(4)));
typedef __bf16 bf16x8 __attribute__((ext_vector_type(8)));

__device__ __forceinline__ float elu_f(float v) {
  return v > 0.0f ? v : (__expf(v) - 1.0f);
}

// Pre-convert W (64x256 f32) into MFMA A-fragment order, bf16.
// Slot s = (chunk ck 0..7, htile 0..3, lane 0..63): holds W[ht*16+(l&15)][ck*32+8*(l>>4) + j], j=0..7
__global__ void wprep_kernel(const float* __restrict__ w, bf16x8* __restrict__ wf) {
  int s = blockIdx.x * 256 + threadIdx.x;  // 0..2047
  int ck = s >> 8;
  int rem = s & 255;
  int ht = rem >> 6;
  int l = rem & 63;
  int h = ht * 16 + (l & 15);
  int c = ck * 32 + ((l >> 4) << 3);
  const float* src = w + h * 256 + c;
  bf16x8 v;
#pragma unroll
  for (int j = 0; j < 8; ++j) v[j] = (__bf16)src[j];
  wf[s] = v;
}

// z1f LDS fragment index swizzle (store and read must match): spreads the
// staging writes (which otherwise hit one 4-bank group 16-wide) across all
// bank groups; reads stay conflict-free (XOR term is quarter-wave-uniform).
__device__ __forceinline__ int swz(int i) { return i ^ ((i >> 4) & 7); }

// PASS 0: compute ELU(conv(features)) and per-block per-channel sum/sumsq partials.
// PASS 1: recompute, apply BN scale/shift, write output.
template <int PASS>
__global__ __launch_bounds__(256, 2) void fused_kernel(
    const float* __restrict__ z0g, const float* __restrict__ z1g,
    const bf16x8* __restrict__ wf, const float* __restrict__ cb,
    const float* __restrict__ sstab, float* __restrict__ partials,
    float* __restrict__ out) {
  __shared__ float z0_lds[16 * 128];  // 8 KB, row-major [x_local][c]
  __shared__ f32x4 z1f[1024];         // 16 KB; logical idx = ((p*2+yt)*4+ck)*64+fl, swizzled
  __shared__ float sred[128];         // per-channel sum / sumsq (PASS0)
  __shared__ float cb_lds[64];
  __shared__ float sc_lds[128];       // scale[64], shift[64] (PASS1)

  const int t = threadIdx.x;
  const int lane = t & 63;
  const int wv = t >> 6;
  const int bid = blockIdx.x;
  const int by = bid & 15, bx = (bid >> 4) & 31, n = bid >> 9;
  const int x0 = bx * 16, y0 = by * 32;

  // ---- staging ----
  {
    int r = t >> 4, cs = t & 15;  // z0: row 0..15, 8-float column segment
    const f32x4* g0 = (const f32x4*)(z0g + (size_t)(n * LL + x0 + r) * DDIM + cs * 8);
    f32x4 a0 = g0[0], a1 = g0[1];
    ((f32x4*)z0_lds)[r * 32 + cs * 2 + 0] = a0;
    ((f32x4*)z0_lds)[r * 32 + cs * 2 + 1] = a1;
#pragma unroll
    for (int s = t; s < 512; s += 256) {  // z1: 32 rows x 16 segs
      int rr = s >> 4, cs1 = s & 15;
      const f32x4* g1 = (const f32x4*)(z1g + (size_t)(n * LL + y0 + rr) * DDIM + cs1 * 8);
      f32x4 b0 = g1[0], b1 = g1[1];
      int yt = rr >> 4, rl = rr & 15, ck = cs1 >> 2, gg = cs1 & 3, fl = gg * 16 + rl;
      int i0 = ((0 * 2 + yt) * 4 + ck) * 64 + fl;
      int i1 = ((1 * 2 + yt) * 4 + ck) * 64 + fl;
      z1f[swz(i0)] = b0;
      z1f[swz(i1)] = b1;
    }
    if (t < 128) sred[t] = 0.0f;
    if (t < 64) cb_lds[t] = cb[t];
    if (PASS == 1 && t < 128) sc_lds[t] = sstab[t];
  }
  __syncthreads();

  f32x4 acc[4][4][2];  // [xi][htile][yt]
  const f32x4 zero4 = {0.f, 0.f, 0.f, 0.f};
#pragma unroll
  for (int xi = 0; xi < 4; ++xi)
#pragma unroll
    for (int ht = 0; ht < 4; ++ht)
#pragma unroll
      for (int yt = 0; yt < 2; ++yt) acc[xi][ht][yt] = zero4;

  // ---- main loop: 4 z-chunks, each feeds dif (ck) and mul (ck+4) MFMAs ----
#pragma unroll
  for (int ckz = 0; ckz < 4; ++ckz) {
    bf16x8 afd[4], afm[4];
#pragma unroll
    for (int ht = 0; ht < 4; ++ht) {
      afd[ht] = wf[(ckz * 4 + ht) * 64 + lane];
      afm[ht] = wf[((ckz + 4) * 4 + ht) * 64 + lane];
    }
    f32x4 b0[2], b1[2];
#pragma unroll
    for (int yt = 0; yt < 2; ++yt) {
      b0[yt] = z1f[swz(((0 * 2 + yt) * 4 + ckz) * 64 + lane)];
      b1[yt] = z1f[swz(((1 * 2 + yt) * 4 + ckz) * 64 + lane)];
    }
#pragma unroll
    for (int xi = 0; xi < 4; ++xi) {
      const int xl = wv * 4 + xi;
      const f32x4* z0p = (const f32x4*)&z0_lds[xl * 128 + ckz * 32 + ((lane >> 4) << 3)];
      f32x4 a0 = z0p[0], a1 = z0p[1];
#pragma unroll
      for (int yt = 0; yt < 2; ++yt) {
        bf16x8 bd, bm;
#pragma unroll
        for (int j = 0; j < 4; ++j) {
          bd[j] = (__bf16)fabsf(a0[j] - b0[yt][j]);
          bd[4 + j] = (__bf16)fabsf(a1[j] - b1[yt][j]);
          bm[j] = (__bf16)(a0[j] * b0[yt][j]);
          bm[4 + j] = (__bf16)(a1[j] * b1[yt][j]);
        }
#pragma unroll
        for (int ht = 0; ht < 4; ++ht) {
          acc[xi][ht][yt] =
              __builtin_amdgcn_mfma_f32_16x16x32_bf16(afd[ht], bd, acc[xi][ht][yt], 0, 0, 0);
          acc[xi][ht][yt] =
              __builtin_amdgcn_mfma_f32_16x16x32_bf16(afm[ht], bm, acc[xi][ht][yt], 0, 0, 0);
        }
      }
    }
  }

  // ---- epilogue ----
  if (PASS == 0) {
    float s1[4][4], s2[4][4];
#pragma unroll
    for (int ht = 0; ht < 4; ++ht)
#pragma unroll
      for (int i = 0; i < 4; ++i) { s1[ht][i] = 0.f; s2[ht][i] = 0.f; }
#pragma unroll
    for (int xi = 0; xi < 4; ++xi)
#pragma unroll
      for (int ht = 0; ht < 4; ++ht)
#pragma unroll
        for (int yt = 0; yt < 2; ++yt)
#pragma unroll
          for (int i = 0; i < 4; ++i) {
            int h = ht * 16 + ((lane >> 4) << 2) + i;
            float v = elu_f(acc[xi][ht][yt][i] + cb_lds[h]);
            s1[ht][i] += v;
            s2[ht][i] += v * v;
          }
#pragma unroll
    for (int ht = 0; ht < 4; ++ht)
#pragma unroll
      for (int i = 0; i < 4; ++i) {
#pragma unroll
        for (int m = 1; m <= 8; m <<= 1) {
          s1[ht][i] += __shfl_xor(s1[ht][i], m, 64);
          s2[ht][i] += __shfl_xor(s2[ht][i], m, 64);
        }
        if ((lane & 15) == 0) {
          int h = ht * 16 + ((lane >> 4) << 2) + i;
          atomicAdd(&sred[h], s1[ht][i]);
          atomicAdd(&sred[64 + h], s2[ht][i]);
        }
      }
    __syncthreads();
    // partials layout: [block][channel_slot] -> coalesced 512B per-block writes
    if (t < 128) partials[(size_t)bid * 128 + t] = sred[t];
  } else {
#pragma unroll
    for (int xi = 0; xi < 4; ++xi) {
      const int x = x0 + wv * 4 + xi;
#pragma unroll
      for (int ht = 0; ht < 4; ++ht)
#pragma unroll
        for (int i = 0; i < 4; ++i) {
          int h = ht * 16 + ((lane >> 4) << 2) + i;
          float sc = sc_lds[h], sh = sc_lds[64 + h];
          float* p = out + ((size_t)(n * HCH + h) * LL + x) * LL + y0 + (lane & 15);
          // yt=0 and yt=1 are the two halves of one 128B line: store back-to-back
          // so L2 write-combines into full-line writebacks (no RMW).
          float v0 = elu_f(acc[xi][ht][0][i] + cb_lds[h]);
          float v1 = elu_f(acc[xi][ht][1][i] + cb_lds[h]);
          p[0] = v0 * sc + sh;
          p[16] = v1 * sc + sh;
        }
    }
  }
}

__global__ void bn_finalize_kernel(const float* __restrict__ partials,
                                   const float* __restrict__ gamma,
                                   const float* __restrict__ beta,
                                   float* __restrict__ sstab) {
  const int h = blockIdx.x, t = threadIdx.x;
  const int lane = t & 63, wv = t >> 6;
  float s1 = 0.f, s2 = 0.f;
  for (int b = t; b < NBLOCKS; b += 256) {
    s1 += partials[(size_t)b * 128 + h];
    s2 += partials[(size_t)b * 128 + 64 + h];
  }
#pragma unroll
  for (int m = 1; m <= 32; m <<= 1) {
    s1 += __shfl_xor(s1, m, 64);
    s2 += __shfl_xor(s2, m, 64);
  }
  __shared__ float r1[4], r2[4];
  if (lane == 0) { r1[wv] = s1; r2[wv] = s2; }
  __syncthreads();
  if (t == 0) {
    float S1 = r1[0] + r1[1] + r1[2] + r1[3];
    float S2 = r2[0] + r2[1] + r2[2] + r2[3];
    const float M = 524288.0f;  // 2 * 512 * 512
    float mean = S1 / M;
    float var = S2 / M - mean * mean;
    var = var < 0.f ? 0.f : var;
    float sc = gamma[h] * rsqrtf(var + 1e-5f);
    sstab[h] = sc;
    sstab[64 + h] = beta[h] - mean * sc;
  }
}

extern "C" void kernel_launch(void* const* d_in, const int* in_sizes, int n_in,
                              void* d_out, int out_size, void* d_ws, size_t ws_size,
                              hipStream_t stream) {
  (void)in_sizes; (void)n_in; (void)out_size; (void)ws_size;
  const float* z0 = (const float*)d_in[0];
  const float* z1 = (const float*)d_in[1];
  const float* w = (const float*)d_in[2];
  const float* cb = (const float*)d_in[3];
  const float* gamma = (const float*)d_in[4];
  const float* beta = (const float*)d_in[5];
  float* out = (float*)d_out;

  char* ws = (char*)d_ws;
  bf16x8* wf = (bf16x8*)ws;                                  // 32 KB
  float* partials = (float*)(ws + 32768);                    // 1024 * 128 * 4 = 512 KB
  float* sstab = (float*)(ws + 32768 + NBLOCKS * 128 * 4);   // 128 floats

  wprep_kernel<<<8, 256, 0, stream>>>(w, wf);
  fused_kernel<0><<<NBLOCKS, 256, 0, stream>>>(z0, z1, wf, cb, nullptr, partials, nullptr);
  bn_finalize_kernel<<<64, 256, 0, stream>>>(partials, gamma, beta, sstab);
  fused_kernel<1><<<NBLOCKS, 256, 0, stream>>>(z0, z1, wf, cb, sstab, partials, out);
}